// Round 15
// baseline (242.400 us; speedup 1.0000x reference)
//
#include <hip/hip_runtime.h>

typedef _Float16 f16;
typedef _Float16 half8 __attribute__((ext_vector_type(8)));
typedef _Float16 half4 __attribute__((ext_vector_type(4)));
typedef __fp16 fp16x2 __attribute__((ext_vector_type(2)));
typedef float f32x4 __attribute__((ext_vector_type(4)));

#define BTOT 65536

// ---------------- workspace layout (bytes) ----------------
static const size_t OFF_FLAT = 0;
static const size_t SZ_FLAT  = (size_t)BTOT * 768 * 2;        // f16 [B][768]
static const size_t OFF_WIT  = OFF_FLAT + SZ_FLAT;            // f16 [256][768]
static const size_t SZ_WIT   = (size_t)256 * 768 * 2;
static const size_t SZ_WT128 = (size_t)208 * 128 * 2;         // 13 tiles * 16 rows
static const size_t SZ_WT64  = (size_t)144 * 64 * 2;          // 9 tiles * 16 rows
static const size_t OFF_WT0  = OFF_WIT + SZ_WIT;
static const size_t OFF_WT1  = OFF_WT0 + SZ_WT128;
static const size_t OFF_WT2  = OFF_WT1 + SZ_WT64;
static const size_t OFF_WT3  = OFF_WT2 + SZ_WT128;
static const size_t OFF_CO   = OFF_WT3 + SZ_WT64;             // f32 [4][64]
static const size_t OFF_C    = OFF_CO + 256 * 4;              // f32 [4]

__device__ __forceinline__ half4 cvt4(float4 v) {
    fp16x2 lo = __builtin_amdgcn_cvt_pkrtz(v.x, v.y);
    fp16x2 hi = __builtin_amdgcn_cvt_pkrtz(v.z, v.w);
    half4 h;
    h[0] = (_Float16)lo[0]; h[1] = (_Float16)lo[1];
    h[2] = (_Float16)hi[0]; h[3] = (_Float16)hi[1];
    return h;
}

// LDS-only barrier (no vmcnt drain; global loads stay in flight).
__device__ __forceinline__ void ldsbar() {
    asm volatile("s_waitcnt lgkmcnt(0)" ::: "memory");
    __builtin_amdgcn_s_barrier();
    __builtin_amdgcn_sched_barrier(0);
}

// =============== weight fusion: wT[n][k] (f16), co, c  (+ wiT transpose) ===============
// blockIdx.y 0..3: per-group fusion; blockIdx.y == 4: wiT[n][k] = wi[k][n]
__global__ __launch_bounds__(256) void pk_all(
    const float* __restrict__ wq0, const float* __restrict__ bq0, const float* __restrict__ wo0, const float* __restrict__ bo0,
    const float* __restrict__ wq1, const float* __restrict__ bq1, const float* __restrict__ wo1, const float* __restrict__ bo1,
    const float* __restrict__ wq2, const float* __restrict__ bq2, const float* __restrict__ wo2, const float* __restrict__ bo2,
    const float* __restrict__ wq3, const float* __restrict__ bq3, const float* __restrict__ wo3, const float* __restrict__ bo3,
    const float* __restrict__ wi,
    f16* __restrict__ wT0, f16* __restrict__ wT1, f16* __restrict__ wT2, f16* __restrict__ wT3,
    f16* __restrict__ wiT, float* __restrict__ coAll, float* __restrict__ cAll)
{
    const int g = blockIdx.y;
    if (g == 4) {   // wiT transpose: 196608 elems over 768 blocks
        int o = blockIdx.x * 256 + threadIdx.x;
        if (o < 196608) {
            int n = o / 768, k = o - n * 768;
            wiT[o] = (f16)wi[k * 256 + n];
        }
        return;
    }
    const float* wqkv; const float* bqkv; const float* wo; const float* bo; f16* wT; int D;
    switch (g) {
        case 0:  wqkv = wq0; bqkv = bq0; wo = wo0; bo = bo0; wT = wT0; D = 128; break;
        case 1:  wqkv = wq1; bqkv = bq1; wo = wo1; bo = bo1; wT = wT1; D = 64;  break;
        case 2:  wqkv = wq2; bqkv = bq2; wo = wo2; bo = bo2; wT = wT2; D = 128; break;
        default: wqkv = wq3; bqkv = bq3; wo = wo3; bo = bo3; wT = wT3; D = 64;  break;
    }
    const int sh = (D == 128) ? 7 : 6;
    const int NT = (D + 81) / 16;            // 13 or 9
    const int NTD = (NT * 16) << sh;
    const int total = NTD + 65;
    const int o = blockIdx.x * 256 + threadIdx.x;
    if (o >= total) return;
    const int s3 = 3 * D;
    const float sc = rsqrtf((float)D);
    if (o < NTD) {
        const int n = o >> sh, k = o & (D - 1);
        float val = 0.f;
        if (n < D) {
            const float* a = wqkv + (size_t)k * s3;
            const float* b = wqkv + (size_t)n * s3 + D;
            float s = 0.f;
            for (int m = 0; m < D; ++m) s += a[m] * b[m];
            val = s * sc;
        } else if (n < D + 64) {
            const int j = n - D;
            const float* a = wqkv + (size_t)k * s3 + 2 * D;
            float s = 0.f;
            for (int m = 0; m < D; ++m) s += a[m] * wo[m * 64 + j];
            val = s;
        } else if (n == D + 64) {
            const float* a = wqkv + (size_t)k * s3;
            float s = 0.f;
            for (int m = 0; m < D; ++m) s += a[m] * bqkv[D + m];
            val = s * sc;
        } else if (n == D + 65) {
            const float* a = wqkv + (size_t)k * s3 + D;
            float s = 0.f;
            for (int m = 0; m < D; ++m) s += a[m] * bqkv[m];
            val = s * sc;
        }
        wT[o] = (f16)val;
    } else if (o < NTD + 64) {
        const int j = o - NTD;
        float s = 0.f;
        for (int m = 0; m < D; ++m) s += bqkv[2 * D + m] * wo[m * 64 + j];
        coAll[g * 64 + j] = s + bo[j];
    } else {
        float s = 0.f;
        for (int m = 0; m < D; ++m) s += bqkv[m] * bqkv[D + m];
        cAll[g] = s * sc;
    }
}

// =============== fused group attention: one 16-batch tile per block ===============
// EXACT round-10 version (best-known: XP = D+8, LDS 33024, no min-waves bound).
// X rows permuted in LDS: row' = word*16 + batch. Two barriers total.
template<int D>
__device__ __forceinline__ void run_group(
    const float* __restrict__ words, const f16* __restrict__ wT,
    const float* __restrict__ coAll, const float* __restrict__ cAll, int gidx,
    f16* __restrict__ flat, int tile, int start, int gbase, int t, char* smem)
{
    constexpr int KST = D / 32;        // mfma K-steps
    constexpr int NT  = (D + 81) / 16; // col tiles: 13 (D=128) / 9 (D=64)
    constexpr int XP  = D + 8;         // padded LDS row
    constexpr int F4  = D / 4;         // float4 per staged row
    constexpr int NLD = 48 * F4 / 256; // 6 or 3 loads/thread

    f16 (*Xs)[XP]  = (f16(*)[XP])(smem);
    f16 (*Zs)[XP]  = (f16(*)[XP])(smem + (size_t)48 * XP * 2);
    f16 (*Zvo)[72] = (f16(*)[72])(smem + (size_t)96 * XP * 2);

    const int wc = t >> 6, lane = t & 63;
    const int lrow = lane & 15, lk = lane >> 4;
    const int r0 = t / F4, c4 = t - r0 * F4;
    const int b0 = tile * 16;

    const f16* wbase = wT + (size_t)lrow * D + lk * 8;

    // ---- stage X (global -> cvt -> LDS, rows permuted) ----
    {
        float4 v[NLD];
        #pragma unroll
        for (int i = 0; i < NLD; ++i) {
            int rr = r0 + i * (256 / F4);
            v[i] = *(const float4*)&words[(size_t)(b0 * 3 + rr) * 384 + start + c4 * 4];
        }
        #pragma unroll
        for (int i = 0; i < NLD; ++i) {
            int rr = r0 + i * (256 / F4);
            int prow = (rr % 3) * 16 + rr / 3;
            *(half4*)&Xs[prow][c4 * 4] = cvt4(v[i]);
        }
    }

    // issue first weight-fragment loads BEFORE the barrier (wave-private; they
    // only touch global memory, so they hide under the LDS-stage wait).
    half8 bA[4], bB[4];
#define LOADB(BUF, KK)                                                          \
    { _Pragma("unroll")                                                         \
      for (int ci = 0; ci < 4; ++ci) {                                          \
          int ct = wc + ci * 4;                                                 \
          if (ct < NT) BUF[ci] = *(const half8*)&wbase[(size_t)ct * 16 * D + (KK) * 32]; \
      } }
    LOADB(bA, 0)

    ldsbar();   // B1: Xs ready

    // ---- phase A: Zfull = X @ [A | Wvo | u | w] ----
    {
        f32x4 acc[3][4];
        #pragma unroll
        for (int rt = 0; rt < 3; ++rt)
            #pragma unroll
            for (int ci = 0; ci < 4; ++ci) acc[rt][ci] = f32x4{0.f, 0.f, 0.f, 0.f};

#define MSTEP(BUF, KK)                                                          \
        { half8 a0 = *(const half8*)&Xs[ 0 + lrow][(KK) * 32 + lk * 8];         \
          half8 a1 = *(const half8*)&Xs[16 + lrow][(KK) * 32 + lk * 8];         \
          half8 a2 = *(const half8*)&Xs[32 + lrow][(KK) * 32 + lk * 8];         \
          _Pragma("unroll")                                                     \
          for (int ci = 0; ci < 4; ++ci) {                                      \
              int ct = wc + ci * 4;                                             \
              if (ct < NT) {                                                    \
                  acc[0][ci] = __builtin_amdgcn_mfma_f32_16x16x32_f16(a0, BUF[ci], acc[0][ci], 0, 0, 0); \
                  acc[1][ci] = __builtin_amdgcn_mfma_f32_16x16x32_f16(a1, BUF[ci], acc[1][ci], 0, 0, 0); \
                  acc[2][ci] = __builtin_amdgcn_mfma_f32_16x16x32_f16(a2, BUF[ci], acc[2][ci], 0, 0, 0); \
              } } }

        #pragma unroll
        for (int kp = 0; kp < KST / 2; ++kp) {
            LOADB(bB, 2 * kp + 1)
            MSTEP(bA, 2 * kp)
            if (2 * kp + 2 < KST) LOADB(bA, 2 * kp + 2)
            MSTEP(bB, 2 * kp + 1)
        }
#undef LOADB
#undef MSTEP

        #pragma unroll
        for (int ci = 0; ci < 4; ++ci) {
            int ct = wc + ci * 4;
            if (ct >= NT) continue;
            int n0 = ct * 16;
            if (n0 + 16 <= D) {
                #pragma unroll
                for (int rt = 0; rt < 3; ++rt)
                    #pragma unroll
                    for (int r = 0; r < 4; ++r)
                        Zs[rt * 16 + lk * 4 + r][n0 + lrow] = (f16)acc[rt][ci][r];
            } else if (n0 < D + 64) {
                #pragma unroll
                for (int rt = 0; rt < 3; ++rt)
                    #pragma unroll
                    for (int r = 0; r < 4; ++r)
                        Zvo[rt * 16 + lk * 4 + r][n0 - D + lrow] = (f16)acc[rt][ci][r];
            } else {
                if (lrow < 2) {
                    #pragma unroll
                    for (int rt = 0; rt < 3; ++rt)
                        #pragma unroll
                        for (int r = 0; r < 4; ++r)
                            ((float*)((char*)&Zs[rt * 16 + lk * 4 + r][D]))[lrow] = acc[rt][ci][r];
                }
            }
        }
    }
    ldsbar();   // B2: Zs/Zvo/xuw ready

    // ---- scoresPV (wave-local): diag-score MFMA + in-reg softmax + PV ----
    if (wc < 3) {
        const float cval = cAll[gidx];
        f32x4 s0v = f32x4{0.f,0.f,0.f,0.f};
        f32x4 s1v = f32x4{0.f,0.f,0.f,0.f};
        f32x4 s2v = f32x4{0.f,0.f,0.f,0.f};
        #pragma unroll
        for (int kk = 0; kk < KST; ++kk) {
            half8 a  = *(const half8*)&Zs[wc * 16 + lrow][kk * 32 + lk * 8];
            half8 b0 = *(const half8*)&Xs[ 0 + lrow][kk * 32 + lk * 8];
            half8 b1 = *(const half8*)&Xs[16 + lrow][kk * 32 + lk * 8];
            half8 b2 = *(const half8*)&Xs[32 + lrow][kk * 32 + lk * 8];
            s0v = __builtin_amdgcn_mfma_f32_16x16x32_f16(a, b0, s0v, 0, 0, 0);
            s1v = __builtin_amdgcn_mfma_f32_16x16x32_f16(a, b1, s1v, 0, 0, 0);
            s2v = __builtin_amdgcn_mfma_f32_16x16x32_f16(a, b2, s2v, 0, 0, 0);
        }
        // diag: lane (bb>>2)*16 + bb holds S[bb][*] in reg r = bb&3
        const int bb = lane & 15;
        const int rr3 = bb & 3;
#define EXT(q) ((rr3 & 2) ? ((rr3 & 1) ? q[3] : q[2]) : ((rr3 & 1) ? q[1] : q[0]))
        float xu = ((const float*)((const char*)&Zs[wc * 16 + bb][D]))[0];
        float sc0 = EXT(s0v) + xu + ((const float*)((const char*)&Zs[ 0 + bb][D]))[1] + cval;
        float sc1 = EXT(s1v) + xu + ((const float*)((const char*)&Zs[16 + bb][D]))[1] + cval;
        float sc2 = EXT(s2v) + xu + ((const float*)((const char*)&Zs[32 + bb][D]))[1] + cval;
#undef EXT
        float m = fmaxf(sc0, fmaxf(sc1, sc2));
        float e0 = __expf(sc0 - m), e1 = __expf(sc1 - m), e2 = __expf(sc2 - m);
        float inv = 1.0f / (e0 + e1 + e2);
        float p0 = e0 * inv, p1 = e1 * inv, p2 = e2 * inv;

        const int c8 = lane & 7;
        float cov[8];
        {
            float4 cA4 = *(const float4*)&coAll[gidx * 64 + c8 * 8];
            float4 cB4 = *(const float4*)&coAll[gidx * 64 + c8 * 8 + 4];
            cov[0]=cA4.x; cov[1]=cA4.y; cov[2]=cA4.z; cov[3]=cA4.w;
            cov[4]=cB4.x; cov[5]=cB4.y; cov[6]=cB4.z; cov[7]=cB4.w;
        }
        #pragma unroll
        for (int it = 0; it < 2; ++it) {
            int bb2 = (lane >> 3) + it * 8;
            int src = ((bb2 >> 2) << 4) | bb2;
            float q0 = __shfl(p0, src);
            float q1 = __shfl(p1, src);
            float q2 = __shfl(p2, src);
            half8 z0 = *(const half8*)&Zvo[ 0 + bb2][c8 * 8];
            half8 z1 = *(const half8*)&Zvo[16 + bb2][c8 * 8];
            half8 z2 = *(const half8*)&Zvo[32 + bb2][c8 * 8];
            half8 o;
            #pragma unroll
            for (int jj = 0; jj < 8; ++jj) {
                float v = q0 * (float)z0[jj] + q1 * (float)z1[jj] + q2 * (float)z2[jj]
                          + cov[jj];
                o[jj] = (f16)fmaxf(v, 0.f);
            }
            *(half8*)&flat[(size_t)(b0 + bb2) * 768 + gbase + wc * 64 + c8 * 8] = o;
        }
    }
}

__global__ __launch_bounds__(256) void k1(
    const float* __restrict__ words,
    const f16* __restrict__ wT0, const f16* __restrict__ wT1,
    const f16* __restrict__ wT2, const f16* __restrict__ wT3,
    const float* __restrict__ coAll, const float* __restrict__ cAll,
    f16* __restrict__ flat)
{
    extern __shared__ char smem[];
    const int t = threadIdx.x;
    const int tile = blockIdx.x;
    const int g = blockIdx.y;
    if (g == 0)
        run_group<128>(words, wT0, coAll, cAll, 0, flat, tile, 0,   0,   t, smem);
    else if (g == 1)
        run_group<64> (words, wT1, coAll, cAll, 1, flat, tile, 128, 192, t, smem);
    else if (g == 2)
        run_group<128>(words, wT2, coAll, cAll, 2, flat, tile, 192, 384, t, smem);
    else
        run_group<64> (words, wT3, coAll, cAll, 3, flat, tile, 320, 576, t, smem);
}

// =============== kernel 2: MLP, M=64 x N=256, 4 blocks/CU ===============
// grid 1024, block 512 (8 waves as 2 row-groups x 4 col-sets); K=768 in 12 chunks.
// Wsh single-buffered (36.9 KB) -> 4 blocks/CU = 4 independent barrier domains.
// A-frags direct from global flat (contiguous per wave); Wsh reg-prefetched.
__global__ __launch_bounds__(512) void k2_mlp(
    const f16* __restrict__ flat, const f16* __restrict__ wiT,
    const float* __restrict__ bi, const float* __restrict__ wout, const float* __restrict__ bout,
    float* __restrict__ out)
{
    __shared__ f16 Wsh[256][72];
    __shared__ float part[64][4];
    __shared__ float bi_l[256], wo_l[256];

    const int t = threadIdx.x;
    const int b0 = blockIdx.x * 64;
    if (t < 256) { bi_l[t] = bi[t]; wo_l[t] = wout[t]; }

    const int wv = t >> 6, lane = t & 63;
    const int wr = wv >> 2, wc = wv & 3;       // 2 x 4 wave grid
    const int lrow = lane & 15, lk = lane >> 4;

    const int pn = t >> 3, pc8 = t & 7;        // staging coords (64 rows x 8 col-chunks)
    half8 wreg[4];
    #pragma unroll
    for (int j = 0; j < 4; ++j)
        wreg[j] = *(const half8*)&wiT[(size_t)(pn + j * 64) * 768 + pc8 * 8];

    const f16* arow0 = flat + (size_t)(b0 + wr * 32 + lrow) * 768;
    const f16* arow1 = flat + (size_t)(b0 + wr * 32 + 16 + lrow) * 768;

    f32x4 acc[2][4];
    #pragma unroll
    for (int i = 0; i < 2; ++i)
        #pragma unroll
        for (int j = 0; j < 4; ++j) acc[i][j] = f32x4{0.f, 0.f, 0.f, 0.f};

    for (int kc = 0; kc < 12; ++kc) {
        #pragma unroll
        for (int j = 0; j < 4; ++j)
            *(half8*)&Wsh[pn + j * 64][pc8 * 8] = wreg[j];
        ldsbar();
        if (kc + 1 < 12) {
            #pragma unroll
            for (int j = 0; j < 4; ++j)
                wreg[j] = *(const half8*)&wiT[(size_t)(pn + j * 64) * 768 + (kc + 1) * 64 + pc8 * 8];
        }
        #pragma unroll
        for (int ks = 0; ks < 2; ++ks) {
            half8 a0 = *(const half8*)&arow0[kc * 64 + ks * 32 + lk * 8];
            half8 a1 = *(const half8*)&arow1[kc * 64 + ks * 32 + lk * 8];
            #pragma unroll
            for (int ct = 0; ct < 4; ++ct) {
                half8 b = *(const half8*)&Wsh[wc * 64 + ct * 16 + lrow][ks * 32 + lk * 8];
                acc[0][ct] = __builtin_amdgcn_mfma_f32_16x16x32_f16(a0, b, acc[0][ct], 0, 0, 0);
                acc[1][ct] = __builtin_amdgcn_mfma_f32_16x16x32_f16(a1, b, acc[1][ct], 0, 0, 0);
            }
        }
        ldsbar();
    }

    float bo0 = bout[0];
    #pragma unroll
    for (int rt = 0; rt < 2; ++rt) {
        #pragma unroll
        for (int r = 0; r < 4; ++r) {
            float s = 0.f;
            #pragma unroll
            for (int ct = 0; ct < 4; ++ct) {
                int col = wc * 64 + ct * 16 + lrow;
                float v = acc[rt][ct][r] + bi_l[col];
                v = fmaxf(v, 0.f);
                s += v * wo_l[col];
            }
            s += __shfl_xor(s, 1, 64); s += __shfl_xor(s, 2, 64);
            s += __shfl_xor(s, 4, 64); s += __shfl_xor(s, 8, 64);
            if (lrow == 0) part[wr * 32 + rt * 16 + lk * 4 + r][wc] = s;
        }
    }
    ldsbar();
    if (t < 64)
        out[b0 + t] = part[t][0] + part[t][1] + part[t][2] + part[t][3] + bo0;
}

// =============== host launcher ===============
extern "C" void kernel_launch(void* const* d_in, const int* in_sizes, int n_in,
                              void* d_out, int out_size, void* d_ws, size_t ws_size,
                              hipStream_t stream)
{
    const float* words = (const float*)d_in[0];
    const float* wq[4] = {(const float*)d_in[1], (const float*)d_in[5], (const float*)d_in[9],  (const float*)d_in[13]};
    const float* bq[4] = {(const float*)d_in[2], (const float*)d_in[6], (const float*)d_in[10], (const float*)d_in[14]};
    const float* wo[4] = {(const float*)d_in[3], (const float*)d_in[7], (const float*)d_in[11], (const float*)d_in[15]};
    const float* bo[4] = {(const float*)d_in[4], (const float*)d_in[8], (const float*)d_in[12], (const float*)d_in[16]};
    const float* wi   = (const float*)d_in[17];
    const float* bi   = (const float*)d_in[18];
    const float* wout = (const float*)d_in[19];
    const float* bout = (const float*)d_in[20];

    char* ws = (char*)d_ws;
    f16*   flat = (f16*)(ws + OFF_FLAT);
    f16*   wiT  = (f16*)(ws + OFF_WIT);
    f16*   wT0  = (f16*)(ws + OFF_WT0);
    f16*   wT1  = (f16*)(ws + OFF_WT1);
    f16*   wT2  = (f16*)(ws + OFF_WT2);
    f16*   wT3  = (f16*)(ws + OFF_WT3);
    float* coA  = (float*)(ws + OFF_CO);
    float* cA   = (float*)(ws + OFF_C);

    // merged weight-prep: y 0..3 = group fusion (needs 105 blocks; extras exit),
    // y == 4 = wiT transpose (needs 768 blocks)
    pk_all<<<dim3(768, 5), 256, 0, stream>>>(
        wq[0], bq[0], wo[0], bo[0], wq[1], bq[1], wo[1], bo[1],
        wq[2], bq[2], wo[2], bo[2], wq[3], bq[3], wo[3], bo[3],
        wi, wT0, wT1, wT2, wT3, wiT, coA, cA);

    // one 16-batch tile per block; dyn LDS = 96*136*2 + 48*72*2 = 33024 B -> 4 blocks/CU
    k1<<<dim3(4096, 4), 256, 33024, stream>>>(words, wT0, wT1, wT2, wT3, coA, cA, flat);

    k2_mlp<<<1024, 512, 0, stream>>>(flat, wiT, bi, wout, bout, (float*)d_out);
}

// Round 16
// 210.715 us; speedup vs baseline: 1.1504x; 1.1504x over previous
//
#include <hip/hip_runtime.h>

typedef _Float16 f16;
typedef _Float16 half8 __attribute__((ext_vector_type(8)));
typedef _Float16 half4 __attribute__((ext_vector_type(4)));
typedef __fp16 fp16x2 __attribute__((ext_vector_type(2)));
typedef float f32x4 __attribute__((ext_vector_type(4)));

#define BTOT 65536

// ---------------- workspace layout (bytes) ----------------
static const size_t OFF_FLAT = 0;
static const size_t SZ_FLAT  = (size_t)BTOT * 768 * 2;        // f16 [B][768]
static const size_t OFF_WIT  = OFF_FLAT + SZ_FLAT;            // f16 [256][768]
static const size_t SZ_WIT   = (size_t)256 * 768 * 2;
static const size_t SZ_WT128 = (size_t)208 * 128 * 2;         // 13 tiles * 16 rows
static const size_t SZ_WT64  = (size_t)144 * 64 * 2;          // 9 tiles * 16 rows
static const size_t OFF_WT0  = OFF_WIT + SZ_WIT;
static const size_t OFF_WT1  = OFF_WT0 + SZ_WT128;
static const size_t OFF_WT2  = OFF_WT1 + SZ_WT64;
static const size_t OFF_WT3  = OFF_WT2 + SZ_WT128;
static const size_t OFF_CO   = OFF_WT3 + SZ_WT64;             // f32 [4][64]
static const size_t OFF_C    = OFF_CO + 256 * 4;              // f32 [4]

__device__ __forceinline__ half4 cvt4(float4 v) {
    fp16x2 lo = __builtin_amdgcn_cvt_pkrtz(v.x, v.y);
    fp16x2 hi = __builtin_amdgcn_cvt_pkrtz(v.z, v.w);
    half4 h;
    h[0] = (_Float16)lo[0]; h[1] = (_Float16)lo[1];
    h[2] = (_Float16)hi[0]; h[3] = (_Float16)hi[1];
    return h;
}

// LDS-only barrier (no vmcnt drain; global loads stay in flight).
__device__ __forceinline__ void ldsbar() {
    asm volatile("s_waitcnt lgkmcnt(0)" ::: "memory");
    __builtin_amdgcn_s_barrier();
    __builtin_amdgcn_sched_barrier(0);
}

// =============== weight prep (merged): group fusion + wiT transpose ===============
// blockIdx.y 0..3: per-group fusion; blockIdx.y == 4: wiT[n][k] = wi[k][n]
__global__ __launch_bounds__(256) void pk_all(
    const float* __restrict__ wq0, const float* __restrict__ bq0, const float* __restrict__ wo0, const float* __restrict__ bo0,
    const float* __restrict__ wq1, const float* __restrict__ bq1, const float* __restrict__ wo1, const float* __restrict__ bo1,
    const float* __restrict__ wq2, const float* __restrict__ bq2, const float* __restrict__ wo2, const float* __restrict__ bo2,
    const float* __restrict__ wq3, const float* __restrict__ bq3, const float* __restrict__ wo3, const float* __restrict__ bo3,
    const float* __restrict__ wi,
    f16* __restrict__ wT0, f16* __restrict__ wT1, f16* __restrict__ wT2, f16* __restrict__ wT3,
    f16* __restrict__ wiT, float* __restrict__ coAll, float* __restrict__ cAll)
{
    const int g = blockIdx.y;
    if (g == 4) {   // wiT transpose: 196608 elems over 768 blocks
        int o = blockIdx.x * 256 + threadIdx.x;
        if (o < 196608) {
            int n = o / 768, k = o - n * 768;
            wiT[o] = (f16)wi[k * 256 + n];
        }
        return;
    }
    const float* wqkv; const float* bqkv; const float* wo; const float* bo; f16* wT; int D;
    switch (g) {
        case 0:  wqkv = wq0; bqkv = bq0; wo = wo0; bo = bo0; wT = wT0; D = 128; break;
        case 1:  wqkv = wq1; bqkv = bq1; wo = wo1; bo = bo1; wT = wT1; D = 64;  break;
        case 2:  wqkv = wq2; bqkv = bq2; wo = wo2; bo = bo2; wT = wT2; D = 128; break;
        default: wqkv = wq3; bqkv = bq3; wo = wo3; bo = bo3; wT = wT3; D = 64;  break;
    }
    const int sh = (D == 128) ? 7 : 6;
    const int NT = (D + 81) / 16;            // 13 or 9
    const int NTD = (NT * 16) << sh;
    const int total = NTD + 65;
    const int o = blockIdx.x * 256 + threadIdx.x;
    if (o >= total) return;
    const int s3 = 3 * D;
    const float sc = rsqrtf((float)D);
    if (o < NTD) {
        const int n = o >> sh, k = o & (D - 1);
        float val = 0.f;
        if (n < D) {
            const float* a = wqkv + (size_t)k * s3;
            const float* b = wqkv + (size_t)n * s3 + D;
            float s = 0.f;
            for (int m = 0; m < D; ++m) s += a[m] * b[m];
            val = s * sc;
        } else if (n < D + 64) {
            const int j = n - D;
            const float* a = wqkv + (size_t)k * s3 + 2 * D;
            float s = 0.f;
            for (int m = 0; m < D; ++m) s += a[m] * wo[m * 64 + j];
            val = s;
        } else if (n == D + 64) {
            const float* a = wqkv + (size_t)k * s3;
            float s = 0.f;
            for (int m = 0; m < D; ++m) s += a[m] * bqkv[D + m];
            val = s * sc;
        } else if (n == D + 65) {
            const float* a = wqkv + (size_t)k * s3 + D;
            float s = 0.f;
            for (int m = 0; m < D; ++m) s += a[m] * bqkv[m];
            val = s * sc;
        }
        wT[o] = (f16)val;
    } else if (o < NTD + 64) {
        const int j = o - NTD;
        float s = 0.f;
        for (int m = 0; m < D; ++m) s += bqkv[2 * D + m] * wo[m * 64 + j];
        coAll[g * 64 + j] = s + bo[j];
    } else {
        float s = 0.f;
        for (int m = 0; m < D; ++m) s += bqkv[m] * bqkv[D + m];
        cAll[g] = s * sc;
    }
}

// =============== fused group attention: one 16-batch tile per block ===============
// EXACT round-10/14 version (best-known: XP = D+8, LDS 33024, no min-waves bound).
// X rows permuted in LDS: row' = word*16 + batch. Two barriers total.
template<int D>
__device__ __forceinline__ void run_group(
    const float* __restrict__ words, const f16* __restrict__ wT,
    const float* __restrict__ coAll, const float* __restrict__ cAll, int gidx,
    f16* __restrict__ flat, int tile, int start, int gbase, int t, char* smem)
{
    constexpr int KST = D / 32;        // mfma K-steps
    constexpr int NT  = (D + 81) / 16; // col tiles: 13 (D=128) / 9 (D=64)
    constexpr int XP  = D + 8;         // padded LDS row
    constexpr int F4  = D / 4;         // float4 per staged row
    constexpr int NLD = 48 * F4 / 256; // 6 or 3 loads/thread

    f16 (*Xs)[XP]  = (f16(*)[XP])(smem);
    f16 (*Zs)[XP]  = (f16(*)[XP])(smem + (size_t)48 * XP * 2);
    f16 (*Zvo)[72] = (f16(*)[72])(smem + (size_t)96 * XP * 2);

    const int wc = t >> 6, lane = t & 63;
    const int lrow = lane & 15, lk = lane >> 4;
    const int r0 = t / F4, c4 = t - r0 * F4;
    const int b0 = tile * 16;

    const f16* wbase = wT + (size_t)lrow * D + lk * 8;

    // ---- stage X (global -> cvt -> LDS, rows permuted) ----
    {
        float4 v[NLD];
        #pragma unroll
        for (int i = 0; i < NLD; ++i) {
            int rr = r0 + i * (256 / F4);
            v[i] = *(const float4*)&words[(size_t)(b0 * 3 + rr) * 384 + start + c4 * 4];
        }
        #pragma unroll
        for (int i = 0; i < NLD; ++i) {
            int rr = r0 + i * (256 / F4);
            int prow = (rr % 3) * 16 + rr / 3;
            *(half4*)&Xs[prow][c4 * 4] = cvt4(v[i]);
        }
    }

    // issue first weight-fragment loads BEFORE the barrier (wave-private; they
    // only touch global memory, so they hide under the LDS-stage wait).
    half8 bA[4], bB[4];
#define LOADB(BUF, KK)                                                          \
    { _Pragma("unroll")                                                         \
      for (int ci = 0; ci < 4; ++ci) {                                          \
          int ct = wc + ci * 4;                                                 \
          if (ct < NT) BUF[ci] = *(const half8*)&wbase[(size_t)ct * 16 * D + (KK) * 32]; \
      } }
    LOADB(bA, 0)

    ldsbar();   // B1: Xs ready

    // ---- phase A: Zfull = X @ [A | Wvo | u | w] ----
    {
        f32x4 acc[3][4];
        #pragma unroll
        for (int rt = 0; rt < 3; ++rt)
            #pragma unroll
            for (int ci = 0; ci < 4; ++ci) acc[rt][ci] = f32x4{0.f, 0.f, 0.f, 0.f};

#define MSTEP(BUF, KK)                                                          \
        { half8 a0 = *(const half8*)&Xs[ 0 + lrow][(KK) * 32 + lk * 8];         \
          half8 a1 = *(const half8*)&Xs[16 + lrow][(KK) * 32 + lk * 8];         \
          half8 a2 = *(const half8*)&Xs[32 + lrow][(KK) * 32 + lk * 8];         \
          _Pragma("unroll")                                                     \
          for (int ci = 0; ci < 4; ++ci) {                                      \
              int ct = wc + ci * 4;                                             \
              if (ct < NT) {                                                    \
                  acc[0][ci] = __builtin_amdgcn_mfma_f32_16x16x32_f16(a0, BUF[ci], acc[0][ci], 0, 0, 0); \
                  acc[1][ci] = __builtin_amdgcn_mfma_f32_16x16x32_f16(a1, BUF[ci], acc[1][ci], 0, 0, 0); \
                  acc[2][ci] = __builtin_amdgcn_mfma_f32_16x16x32_f16(a2, BUF[ci], acc[2][ci], 0, 0, 0); \
              } } }

        #pragma unroll
        for (int kp = 0; kp < KST / 2; ++kp) {
            LOADB(bB, 2 * kp + 1)
            MSTEP(bA, 2 * kp)
            if (2 * kp + 2 < KST) LOADB(bA, 2 * kp + 2)
            MSTEP(bB, 2 * kp + 1)
        }
#undef LOADB
#undef MSTEP

        #pragma unroll
        for (int ci = 0; ci < 4; ++ci) {
            int ct = wc + ci * 4;
            if (ct >= NT) continue;
            int n0 = ct * 16;
            if (n0 + 16 <= D) {
                #pragma unroll
                for (int rt = 0; rt < 3; ++rt)
                    #pragma unroll
                    for (int r = 0; r < 4; ++r)
                        Zs[rt * 16 + lk * 4 + r][n0 + lrow] = (f16)acc[rt][ci][r];
            } else if (n0 < D + 64) {
                #pragma unroll
                for (int rt = 0; rt < 3; ++rt)
                    #pragma unroll
                    for (int r = 0; r < 4; ++r)
                        Zvo[rt * 16 + lk * 4 + r][n0 - D + lrow] = (f16)acc[rt][ci][r];
            } else {
                if (lrow < 2) {
                    #pragma unroll
                    for (int rt = 0; rt < 3; ++rt)
                        #pragma unroll
                        for (int r = 0; r < 4; ++r)
                            ((float*)((char*)&Zs[rt * 16 + lk * 4 + r][D]))[lrow] = acc[rt][ci][r];
                }
            }
        }
    }
    ldsbar();   // B2: Zs/Zvo/xuw ready

    // ---- scoresPV (wave-local): diag-score MFMA + in-reg softmax + PV ----
    if (wc < 3) {
        const float cval = cAll[gidx];
        f32x4 s0v = f32x4{0.f,0.f,0.f,0.f};
        f32x4 s1v = f32x4{0.f,0.f,0.f,0.f};
        f32x4 s2v = f32x4{0.f,0.f,0.f,0.f};
        #pragma unroll
        for (int kk = 0; kk < KST; ++kk) {
            half8 a  = *(const half8*)&Zs[wc * 16 + lrow][kk * 32 + lk * 8];
            half8 b0 = *(const half8*)&Xs[ 0 + lrow][kk * 32 + lk * 8];
            half8 b1 = *(const half8*)&Xs[16 + lrow][kk * 32 + lk * 8];
            half8 b2 = *(const half8*)&Xs[32 + lrow][kk * 32 + lk * 8];
            s0v = __builtin_amdgcn_mfma_f32_16x16x32_f16(a, b0, s0v, 0, 0, 0);
            s1v = __builtin_amdgcn_mfma_f32_16x16x32_f16(a, b1, s1v, 0, 0, 0);
            s2v = __builtin_amdgcn_mfma_f32_16x16x32_f16(a, b2, s2v, 0, 0, 0);
        }
        // diag: lane (bb>>2)*16 + bb holds S[bb][*] in reg r = bb&3
        const int bb = lane & 15;
        const int rr3 = bb & 3;
#define EXT(q) ((rr3 & 2) ? ((rr3 & 1) ? q[3] : q[2]) : ((rr3 & 1) ? q[1] : q[0]))
        float xu = ((const float*)((const char*)&Zs[wc * 16 + bb][D]))[0];
        float sc0 = EXT(s0v) + xu + ((const float*)((const char*)&Zs[ 0 + bb][D]))[1] + cval;
        float sc1 = EXT(s1v) + xu + ((const float*)((const char*)&Zs[16 + bb][D]))[1] + cval;
        float sc2 = EXT(s2v) + xu + ((const float*)((const char*)&Zs[32 + bb][D]))[1] + cval;
#undef EXT
        float m = fmaxf(sc0, fmaxf(sc1, sc2));
        float e0 = __expf(sc0 - m), e1 = __expf(sc1 - m), e2 = __expf(sc2 - m);
        float inv = 1.0f / (e0 + e1 + e2);
        float p0 = e0 * inv, p1 = e1 * inv, p2 = e2 * inv;

        const int c8 = lane & 7;
        float cov[8];
        {
            float4 cA4 = *(const float4*)&coAll[gidx * 64 + c8 * 8];
            float4 cB4 = *(const float4*)&coAll[gidx * 64 + c8 * 8 + 4];
            cov[0]=cA4.x; cov[1]=cA4.y; cov[2]=cA4.z; cov[3]=cA4.w;
            cov[4]=cB4.x; cov[5]=cB4.y; cov[6]=cB4.z; cov[7]=cB4.w;
        }
        #pragma unroll
        for (int it = 0; it < 2; ++it) {
            int bb2 = (lane >> 3) + it * 8;
            int src = ((bb2 >> 2) << 4) | bb2;
            float q0 = __shfl(p0, src);
            float q1 = __shfl(p1, src);
            float q2 = __shfl(p2, src);
            half8 z0 = *(const half8*)&Zvo[ 0 + bb2][c8 * 8];
            half8 z1 = *(const half8*)&Zvo[16 + bb2][c8 * 8];
            half8 z2 = *(const half8*)&Zvo[32 + bb2][c8 * 8];
            half8 o;
            #pragma unroll
            for (int jj = 0; jj < 8; ++jj) {
                float v = q0 * (float)z0[jj] + q1 * (float)z1[jj] + q2 * (float)z2[jj]
                          + cov[jj];
                o[jj] = (f16)fmaxf(v, 0.f);
            }
            *(half8*)&flat[(size_t)(b0 + bb2) * 768 + gbase + wc * 64 + c8 * 8] = o;
        }
    }
}

__global__ __launch_bounds__(256) void k1(
    const float* __restrict__ words,
    const f16* __restrict__ wT0, const f16* __restrict__ wT1,
    const f16* __restrict__ wT2, const f16* __restrict__ wT3,
    const float* __restrict__ coAll, const float* __restrict__ cAll,
    f16* __restrict__ flat)
{
    extern __shared__ char smem[];
    const int t = threadIdx.x;
    const int tile = blockIdx.x;
    const int g = blockIdx.y;
    if (g == 0)
        run_group<128>(words, wT0, coAll, cAll, 0, flat, tile, 0,   0,   t, smem);
    else if (g == 1)
        run_group<64> (words, wT1, coAll, cAll, 1, flat, tile, 128, 192, t, smem);
    else if (g == 2)
        run_group<128>(words, wT2, coAll, cAll, 2, flat, tile, 192, 384, t, smem);
    else
        run_group<64> (words, wT3, coAll, cAll, 3, flat, tile, 320, 576, t, smem);
}

// =============== kernel 2: MLP with double-buffered Wsh (round-14 proven) ===============
// grid 512, block 512 (8 waves: 4 row-groups x 2 col-sets); M=128, N=256, K=768.
__global__ __launch_bounds__(512) void k2_mlp(
    const f16* __restrict__ flat, const f16* __restrict__ wiT,
    const float* __restrict__ bi, const float* __restrict__ wout, const float* __restrict__ bout,
    float* __restrict__ out)
{
    __shared__ f16 Wsh[2][256][72];
    __shared__ float part[128][2];
    __shared__ float bi_l[256], wo_l[256];

    const int t = threadIdx.x;
    const int b0 = blockIdx.x * 128;
    if (t < 256) { bi_l[t] = bi[t]; wo_l[t] = wout[t]; }

    const int wv = t >> 6, lane = t & 63;
    const int wr = wv >> 1, wc = wv & 1;
    const int lrow = lane & 15, lk = lane >> 4;

    const int pn = t >> 3, pc8 = t & 7;
    half8 wreg[4];
    #pragma unroll
    for (int j = 0; j < 4; ++j)
        wreg[j] = *(const half8*)&wiT[(size_t)(pn + j * 64) * 768 + pc8 * 8];
    #pragma unroll
    for (int j = 0; j < 4; ++j)
        *(half8*)&Wsh[0][pn + j * 64][pc8 * 8] = wreg[j];

    const f16* arow0 = flat + (size_t)(b0 + wr * 32 + lrow) * 768;
    const f16* arow1 = flat + (size_t)(b0 + wr * 32 + 16 + lrow) * 768;

    f32x4 acc[2][8];
    #pragma unroll
    for (int i = 0; i < 2; ++i)
        #pragma unroll
        for (int j = 0; j < 8; ++j) acc[i][j] = f32x4{0.f, 0.f, 0.f, 0.f};

    for (int kc = 0; kc < 12; ++kc) {
        const int cur = kc & 1;
        if (kc + 1 < 12) {
            #pragma unroll
            for (int j = 0; j < 4; ++j)
                wreg[j] = *(const half8*)&wiT[(size_t)(pn + j * 64) * 768 + (kc + 1) * 64 + pc8 * 8];
        }
        ldsbar();   // Wsh[cur] ready (written at end of kc-1, or prologue for kc=0)
        #pragma unroll
        for (int ks = 0; ks < 2; ++ks) {
            half8 a0 = *(const half8*)&arow0[kc * 64 + ks * 32 + lk * 8];
            half8 a1 = *(const half8*)&arow1[kc * 64 + ks * 32 + lk * 8];
            #pragma unroll
            for (int ct = 0; ct < 8; ++ct) {
                half8 b = *(const half8*)&Wsh[cur][wc * 128 + ct * 16 + lrow][ks * 32 + lk * 8];
                acc[0][ct] = __builtin_amdgcn_mfma_f32_16x16x32_f16(a0, b, acc[0][ct], 0, 0, 0);
                acc[1][ct] = __builtin_amdgcn_mfma_f32_16x16x32_f16(a1, b, acc[1][ct], 0, 0, 0);
            }
        }
        if (kc + 1 < 12) {
            #pragma unroll
            for (int j = 0; j < 4; ++j)
                *(half8*)&Wsh[cur ^ 1][pn + j * 64][pc8 * 8] = wreg[j];
        }
    }

    float bo0 = bout[0];
    #pragma unroll
    for (int rt = 0; rt < 2; ++rt) {
        #pragma unroll
        for (int r = 0; r < 4; ++r) {
            float s = 0.f;
            #pragma unroll
            for (int ct = 0; ct < 8; ++ct) {
                int col = wc * 128 + ct * 16 + lrow;
                float v = acc[rt][ct][r] + bi_l[col];
                v = fmaxf(v, 0.f);
                s += v * wo_l[col];
            }
            s += __shfl_xor(s, 1, 64); s += __shfl_xor(s, 2, 64);
            s += __shfl_xor(s, 4, 64); s += __shfl_xor(s, 8, 64);
            if (lrow == 0) part[wr * 32 + rt * 16 + lk * 4 + r][wc] = s;
        }
    }
    ldsbar();
    if (t < 128) out[b0 + t] = part[t][0] + part[t][1] + bo0;
}

// =============== host launcher ===============
extern "C" void kernel_launch(void* const* d_in, const int* in_sizes, int n_in,
                              void* d_out, int out_size, void* d_ws, size_t ws_size,
                              hipStream_t stream)
{
    const float* words = (const float*)d_in[0];
    const float* wq[4] = {(const float*)d_in[1], (const float*)d_in[5], (const float*)d_in[9],  (const float*)d_in[13]};
    const float* bq[4] = {(const float*)d_in[2], (const float*)d_in[6], (const float*)d_in[10], (const float*)d_in[14]};
    const float* wo[4] = {(const float*)d_in[3], (const float*)d_in[7], (const float*)d_in[11], (const float*)d_in[15]};
    const float* bo[4] = {(const float*)d_in[4], (const float*)d_in[8], (const float*)d_in[12], (const float*)d_in[16]};
    const float* wi   = (const float*)d_in[17];
    const float* bi   = (const float*)d_in[18];
    const float* wout = (const float*)d_in[19];
    const float* bout = (const float*)d_in[20];

    char* ws = (char*)d_ws;
    f16*   flat = (f16*)(ws + OFF_FLAT);
    f16*   wiT  = (f16*)(ws + OFF_WIT);
    f16*   wT0  = (f16*)(ws + OFF_WT0);
    f16*   wT1  = (f16*)(ws + OFF_WT1);
    f16*   wT2  = (f16*)(ws + OFF_WT2);
    f16*   wT3  = (f16*)(ws + OFF_WT3);
    float* coA  = (float*)(ws + OFF_CO);
    float* cA   = (float*)(ws + OFF_C);

    // merged weight-prep: y 0..3 = group fusion (needs <=105 blocks; extras exit),
    // y == 4 = wiT transpose (768 blocks)
    pk_all<<<dim3(768, 5), 256, 0, stream>>>(
        wq[0], bq[0], wo[0], bo[0], wq[1], bq[1], wo[1], bo[1],
        wq[2], bq[2], wo[2], bo[2], wq[3], bq[3], wo[3], bo[3],
        wi, wT0, wT1, wT2, wT3, wiT, coA, cA);

    // one 16-batch tile per block; dyn LDS = 96*136*2 + 48*72*2 = 33024 B -> 4 blocks/CU
    k1<<<dim3(4096, 4), 256, 33024, stream>>>(words, wT0, wT1, wT2, wT3, coA, cA, flat);

    k2_mlp<<<512, 512, 0, stream>>>(flat, wiT, bi, wout, bout, (float*)d_out);
}

// Round 17
// 204.657 us; speedup vs baseline: 1.1844x; 1.0296x over previous
//
#include <hip/hip_runtime.h>

typedef _Float16 f16;
typedef _Float16 half8 __attribute__((ext_vector_type(8)));
typedef _Float16 half4 __attribute__((ext_vector_type(4)));
typedef __fp16 fp16x2 __attribute__((ext_vector_type(2)));
typedef float f32x4 __attribute__((ext_vector_type(4)));

#define BTOT 65536

// ---------------- workspace layout (bytes) ----------------
static const size_t OFF_FLAT = 0;
static const size_t SZ_FLAT  = (size_t)BTOT * 768 * 2;        // f16 [B][768]
static const size_t OFF_WIT  = OFF_FLAT + SZ_FLAT;            // f16 [256][768]
static const size_t SZ_WIT   = (size_t)256 * 768 * 2;
static const size_t SZ_WT128 = (size_t)208 * 128 * 2;         // 13 tiles * 16 rows
static const size_t SZ_WT64  = (size_t)144 * 64 * 2;          // 9 tiles * 16 rows
static const size_t OFF_WT0  = OFF_WIT + SZ_WIT;
static const size_t OFF_WT1  = OFF_WT0 + SZ_WT128;
static const size_t OFF_WT2  = OFF_WT1 + SZ_WT64;
static const size_t OFF_WT3  = OFF_WT2 + SZ_WT128;
static const size_t OFF_CO   = OFF_WT3 + SZ_WT64;             // f32 [4][64]
static const size_t OFF_C    = OFF_CO + 256 * 4;              // f32 [4]

__device__ __forceinline__ half4 cvt4(float4 v) {
    fp16x2 lo = __builtin_amdgcn_cvt_pkrtz(v.x, v.y);
    fp16x2 hi = __builtin_amdgcn_cvt_pkrtz(v.z, v.w);
    half4 h;
    h[0] = (_Float16)lo[0]; h[1] = (_Float16)lo[1];
    h[2] = (_Float16)hi[0]; h[3] = (_Float16)hi[1];
    return h;
}

// LDS-only barrier (no vmcnt drain; global loads stay in flight).
__device__ __forceinline__ void ldsbar() {
    asm volatile("s_waitcnt lgkmcnt(0)" ::: "memory");
    __builtin_amdgcn_s_barrier();
    __builtin_amdgcn_sched_barrier(0);
}

// =============== weight fusion: wT[n][k] (f16), co, c ===============
__global__ __launch_bounds__(256) void pk_fuse(
    const float* __restrict__ wq0, const float* __restrict__ bq0, const float* __restrict__ wo0, const float* __restrict__ bo0,
    const float* __restrict__ wq1, const float* __restrict__ bq1, const float* __restrict__ wo1, const float* __restrict__ bo1,
    const float* __restrict__ wq2, const float* __restrict__ bq2, const float* __restrict__ wo2, const float* __restrict__ bo2,
    const float* __restrict__ wq3, const float* __restrict__ bq3, const float* __restrict__ wo3, const float* __restrict__ bo3,
    f16* __restrict__ wT0, f16* __restrict__ wT1, f16* __restrict__ wT2, f16* __restrict__ wT3,
    float* __restrict__ coAll, float* __restrict__ cAll)
{
    const int g = blockIdx.y;
    const float* wqkv; const float* bqkv; const float* wo; const float* bo; f16* wT; int D;
    switch (g) {
        case 0:  wqkv = wq0; bqkv = bq0; wo = wo0; bo = bo0; wT = wT0; D = 128; break;
        case 1:  wqkv = wq1; bqkv = bq1; wo = wo1; bo = bo1; wT = wT1; D = 64;  break;
        case 2:  wqkv = wq2; bqkv = bq2; wo = wo2; bo = bo2; wT = wT2; D = 128; break;
        default: wqkv = wq3; bqkv = bq3; wo = wo3; bo = bo3; wT = wT3; D = 64;  break;
    }
    const int sh = (D == 128) ? 7 : 6;
    const int NT = (D + 81) / 16;            // 13 or 9
    const int NTD = (NT * 16) << sh;
    const int total = NTD + 65;
    const int o = blockIdx.x * 256 + threadIdx.x;
    if (o >= total) return;
    const int s3 = 3 * D;
    const float sc = rsqrtf((float)D);
    if (o < NTD) {
        const int n = o >> sh, k = o & (D - 1);
        float val = 0.f;
        if (n < D) {
            const float* a = wqkv + (size_t)k * s3;
            const float* b = wqkv + (size_t)n * s3 + D;
            float s = 0.f;
            for (int m = 0; m < D; ++m) s += a[m] * b[m];
            val = s * sc;
        } else if (n < D + 64) {
            const int j = n - D;
            const float* a = wqkv + (size_t)k * s3 + 2 * D;
            float s = 0.f;
            for (int m = 0; m < D; ++m) s += a[m] * wo[m * 64 + j];
            val = s;
        } else if (n == D + 64) {
            const float* a = wqkv + (size_t)k * s3;
            float s = 0.f;
            for (int m = 0; m < D; ++m) s += a[m] * bqkv[D + m];
            val = s * sc;
        } else if (n == D + 65) {
            const float* a = wqkv + (size_t)k * s3 + D;
            float s = 0.f;
            for (int m = 0; m < D; ++m) s += a[m] * bqkv[m];
            val = s * sc;
        }
        wT[o] = (f16)val;
    } else if (o < NTD + 64) {
        const int j = o - NTD;
        float s = 0.f;
        for (int m = 0; m < D; ++m) s += bqkv[2 * D + m] * wo[m * 64 + j];
        coAll[g * 64 + j] = s + bo[j];
    } else {
        float s = 0.f;
        for (int m = 0; m < D; ++m) s += bqkv[m] * bqkv[D + m];
        cAll[g] = s * sc;
    }
}

// wiT[n][k] = (f16) wi[k][n]  (wi is [768][256])
__global__ __launch_bounds__(256) void pk_wit(const float* __restrict__ wi, f16* __restrict__ wiT)
{
    int o = blockIdx.x * 256 + threadIdx.x;    // 196608 outputs
    int n = o / 768, k = o - n * 768;
    wiT[o] = (f16)wi[k * 256 + n];
}

// =============== fused group attention: one 16-batch tile per block ===============
// Best-known (round 10/14): XP = D+8, LDS 33024, no min-waves bound.
// X rows permuted in LDS: row' = word*16 + batch. Two barriers total.
template<int D>
__device__ __forceinline__ void run_group(
    const float* __restrict__ words, const f16* __restrict__ wT,
    const float* __restrict__ coAll, const float* __restrict__ cAll, int gidx,
    f16* __restrict__ flat, int tile, int start, int gbase, int t, char* smem)
{
    constexpr int KST = D / 32;        // mfma K-steps
    constexpr int NT  = (D + 81) / 16; // col tiles: 13 (D=128) / 9 (D=64)
    constexpr int XP  = D + 8;         // padded LDS row
    constexpr int F4  = D / 4;         // float4 per staged row
    constexpr int NLD = 48 * F4 / 256; // 6 or 3 loads/thread

    f16 (*Xs)[XP]  = (f16(*)[XP])(smem);
    f16 (*Zs)[XP]  = (f16(*)[XP])(smem + (size_t)48 * XP * 2);
    f16 (*Zvo)[72] = (f16(*)[72])(smem + (size_t)96 * XP * 2);

    const int wc = t >> 6, lane = t & 63;
    const int lrow = lane & 15, lk = lane >> 4;
    const int r0 = t / F4, c4 = t - r0 * F4;
    const int b0 = tile * 16;

    const f16* wbase = wT + (size_t)lrow * D + lk * 8;

    // ---- stage X (global -> cvt -> LDS, rows permuted) ----
    {
        float4 v[NLD];
        #pragma unroll
        for (int i = 0; i < NLD; ++i) {
            int rr = r0 + i * (256 / F4);
            v[i] = *(const float4*)&words[(size_t)(b0 * 3 + rr) * 384 + start + c4 * 4];
        }
        #pragma unroll
        for (int i = 0; i < NLD; ++i) {
            int rr = r0 + i * (256 / F4);
            int prow = (rr % 3) * 16 + rr / 3;
            *(half4*)&Xs[prow][c4 * 4] = cvt4(v[i]);
        }
    }

    // issue first weight-fragment loads BEFORE the barrier (wave-private; they
    // only touch global memory, so they hide under the LDS-stage wait).
    half8 bA[4], bB[4];
#define LOADB(BUF, KK)                                                          \
    { _Pragma("unroll")                                                         \
      for (int ci = 0; ci < 4; ++ci) {                                          \
          int ct = wc + ci * 4;                                                 \
          if (ct < NT) BUF[ci] = *(const half8*)&wbase[(size_t)ct * 16 * D + (KK) * 32]; \
      } }
    LOADB(bA, 0)

    ldsbar();   // B1: Xs ready

    // ---- phase A: Zfull = X @ [A | Wvo | u | w] ----
    {
        f32x4 acc[3][4];
        #pragma unroll
        for (int rt = 0; rt < 3; ++rt)
            #pragma unroll
            for (int ci = 0; ci < 4; ++ci) acc[rt][ci] = f32x4{0.f, 0.f, 0.f, 0.f};

#define MSTEP(BUF, KK)                                                          \
        { half8 a0 = *(const half8*)&Xs[ 0 + lrow][(KK) * 32 + lk * 8];         \
          half8 a1 = *(const half8*)&Xs[16 + lrow][(KK) * 32 + lk * 8];         \
          half8 a2 = *(const half8*)&Xs[32 + lrow][(KK) * 32 + lk * 8];         \
          _Pragma("unroll")                                                     \
          for (int ci = 0; ci < 4; ++ci) {                                      \
              int ct = wc + ci * 4;                                             \
              if (ct < NT) {                                                    \
                  acc[0][ci] = __builtin_amdgcn_mfma_f32_16x16x32_f16(a0, BUF[ci], acc[0][ci], 0, 0, 0); \
                  acc[1][ci] = __builtin_amdgcn_mfma_f32_16x16x32_f16(a1, BUF[ci], acc[1][ci], 0, 0, 0); \
                  acc[2][ci] = __builtin_amdgcn_mfma_f32_16x16x32_f16(a2, BUF[ci], acc[2][ci], 0, 0, 0); \
              } } }

        #pragma unroll
        for (int kp = 0; kp < KST / 2; ++kp) {
            LOADB(bB, 2 * kp + 1)
            MSTEP(bA, 2 * kp)
            if (2 * kp + 2 < KST) LOADB(bA, 2 * kp + 2)
            MSTEP(bB, 2 * kp + 1)
        }
#undef LOADB
#undef MSTEP

        #pragma unroll
        for (int ci = 0; ci < 4; ++ci) {
            int ct = wc + ci * 4;
            if (ct >= NT) continue;
            int n0 = ct * 16;
            if (n0 + 16 <= D) {
                #pragma unroll
                for (int rt = 0; rt < 3; ++rt)
                    #pragma unroll
                    for (int r = 0; r < 4; ++r)
                        Zs[rt * 16 + lk * 4 + r][n0 + lrow] = (f16)acc[rt][ci][r];
            } else if (n0 < D + 64) {
                #pragma unroll
                for (int rt = 0; rt < 3; ++rt)
                    #pragma unroll
                    for (int r = 0; r < 4; ++r)
                        Zvo[rt * 16 + lk * 4 + r][n0 - D + lrow] = (f16)acc[rt][ci][r];
            } else {
                if (lrow < 2) {
                    #pragma unroll
                    for (int rt = 0; rt < 3; ++rt)
                        #pragma unroll
                        for (int r = 0; r < 4; ++r)
                            ((float*)((char*)&Zs[rt * 16 + lk * 4 + r][D]))[lrow] = acc[rt][ci][r];
                }
            }
        }
    }
    ldsbar();   // B2: Zs/Zvo/xuw ready

    // ---- scoresPV (wave-local): diag-score MFMA + in-reg softmax + PV ----
    if (wc < 3) {
        const float cval = cAll[gidx];
        f32x4 s0v = f32x4{0.f,0.f,0.f,0.f};
        f32x4 s1v = f32x4{0.f,0.f,0.f,0.f};
        f32x4 s2v = f32x4{0.f,0.f,0.f,0.f};
        #pragma unroll
        for (int kk = 0; kk < KST; ++kk) {
            half8 a  = *(const half8*)&Zs[wc * 16 + lrow][kk * 32 + lk * 8];
            half8 b0 = *(const half8*)&Xs[ 0 + lrow][kk * 32 + lk * 8];
            half8 b1 = *(const half8*)&Xs[16 + lrow][kk * 32 + lk * 8];
            half8 b2 = *(const half8*)&Xs[32 + lrow][kk * 32 + lk * 8];
            s0v = __builtin_amdgcn_mfma_f32_16x16x32_f16(a, b0, s0v, 0, 0, 0);
            s1v = __builtin_amdgcn_mfma_f32_16x16x32_f16(a, b1, s1v, 0, 0, 0);
            s2v = __builtin_amdgcn_mfma_f32_16x16x32_f16(a, b2, s2v, 0, 0, 0);
        }
        // diag: lane (bb>>2)*16 + bb holds S[bb][*] in reg r = bb&3
        const int bb = lane & 15;
        const int rr3 = bb & 3;
#define EXT(q) ((rr3 & 2) ? ((rr3 & 1) ? q[3] : q[2]) : ((rr3 & 1) ? q[1] : q[0]))
        float xu = ((const float*)((const char*)&Zs[wc * 16 + bb][D]))[0];
        float sc0 = EXT(s0v) + xu + ((const float*)((const char*)&Zs[ 0 + bb][D]))[1] + cval;
        float sc1 = EXT(s1v) + xu + ((const float*)((const char*)&Zs[16 + bb][D]))[1] + cval;
        float sc2 = EXT(s2v) + xu + ((const float*)((const char*)&Zs[32 + bb][D]))[1] + cval;
#undef EXT
        float m = fmaxf(sc0, fmaxf(sc1, sc2));
        float e0 = __expf(sc0 - m), e1 = __expf(sc1 - m), e2 = __expf(sc2 - m);
        float inv = 1.0f / (e0 + e1 + e2);
        float p0 = e0 * inv, p1 = e1 * inv, p2 = e2 * inv;

        const int c8 = lane & 7;
        float cov[8];
        {
            float4 cA4 = *(const float4*)&coAll[gidx * 64 + c8 * 8];
            float4 cB4 = *(const float4*)&coAll[gidx * 64 + c8 * 8 + 4];
            cov[0]=cA4.x; cov[1]=cA4.y; cov[2]=cA4.z; cov[3]=cA4.w;
            cov[4]=cB4.x; cov[5]=cB4.y; cov[6]=cB4.z; cov[7]=cB4.w;
        }
        #pragma unroll
        for (int it = 0; it < 2; ++it) {
            int bb2 = (lane >> 3) + it * 8;
            int src = ((bb2 >> 2) << 4) | bb2;
            float q0 = __shfl(p0, src);
            float q1 = __shfl(p1, src);
            float q2 = __shfl(p2, src);
            half8 z0 = *(const half8*)&Zvo[ 0 + bb2][c8 * 8];
            half8 z1 = *(const half8*)&Zvo[16 + bb2][c8 * 8];
            half8 z2 = *(const half8*)&Zvo[32 + bb2][c8 * 8];
            half8 o;
            #pragma unroll
            for (int jj = 0; jj < 8; ++jj) {
                float v = q0 * (float)z0[jj] + q1 * (float)z1[jj] + q2 * (float)z2[jj]
                          + cov[jj];
                o[jj] = (f16)fmaxf(v, 0.f);
            }
            *(half8*)&flat[(size_t)(b0 + bb2) * 768 + gbase + wc * 64 + c8 * 8] = o;
        }
    }
}

__global__ __launch_bounds__(256) void k1(
    const float* __restrict__ words,
    const f16* __restrict__ wT0, const f16* __restrict__ wT1,
    const f16* __restrict__ wT2, const f16* __restrict__ wT3,
    const float* __restrict__ coAll, const float* __restrict__ cAll,
    f16* __restrict__ flat)
{
    extern __shared__ char smem[];
    const int t = threadIdx.x;
    const int tile = blockIdx.x;
    const int g = blockIdx.y;
    if (g == 0)
        run_group<128>(words, wT0, coAll, cAll, 0, flat, tile, 0,   0,   t, smem);
    else if (g == 1)
        run_group<64> (words, wT1, coAll, cAll, 1, flat, tile, 128, 192, t, smem);
    else if (g == 2)
        run_group<128>(words, wT2, coAll, cAll, 2, flat, tile, 192, 384, t, smem);
    else
        run_group<64> (words, wT3, coAll, cAll, 3, flat, tile, 320, 576, t, smem);
}

// =============== kernel 2: MLP with double-buffered Wsh (round-14 proven) ===============
// grid 512, block 512 (8 waves: 4 row-groups x 2 col-sets); M=128, N=256, K=768.
__global__ __launch_bounds__(512) void k2_mlp(
    const f16* __restrict__ flat, const f16* __restrict__ wiT,
    const float* __restrict__ bi, const float* __restrict__ wout, const float* __restrict__ bout,
    float* __restrict__ out)
{
    __shared__ f16 Wsh[2][256][72];
    __shared__ float part[128][2];
    __shared__ float bi_l[256], wo_l[256];

    const int t = threadIdx.x;
    const int b0 = blockIdx.x * 128;
    if (t < 256) { bi_l[t] = bi[t]; wo_l[t] = wout[t]; }

    const int wv = t >> 6, lane = t & 63;
    const int wr = wv >> 1, wc = wv & 1;
    const int lrow = lane & 15, lk = lane >> 4;

    const int pn = t >> 3, pc8 = t & 7;
    half8 wreg[4];
    #pragma unroll
    for (int j = 0; j < 4; ++j)
        wreg[j] = *(const half8*)&wiT[(size_t)(pn + j * 64) * 768 + pc8 * 8];
    #pragma unroll
    for (int j = 0; j < 4; ++j)
        *(half8*)&Wsh[0][pn + j * 64][pc8 * 8] = wreg[j];

    const f16* arow0 = flat + (size_t)(b0 + wr * 32 + lrow) * 768;
    const f16* arow1 = flat + (size_t)(b0 + wr * 32 + 16 + lrow) * 768;

    f32x4 acc[2][8];
    #pragma unroll
    for (int i = 0; i < 2; ++i)
        #pragma unroll
        for (int j = 0; j < 8; ++j) acc[i][j] = f32x4{0.f, 0.f, 0.f, 0.f};

    for (int kc = 0; kc < 12; ++kc) {
        const int cur = kc & 1;
        if (kc + 1 < 12) {
            #pragma unroll
            for (int j = 0; j < 4; ++j)
                wreg[j] = *(const half8*)&wiT[(size_t)(pn + j * 64) * 768 + (kc + 1) * 64 + pc8 * 8];
        }
        ldsbar();   // Wsh[cur] ready (written at end of kc-1, or prologue for kc=0)
        #pragma unroll
        for (int ks = 0; ks < 2; ++ks) {
            half8 a0 = *(const half8*)&arow0[kc * 64 + ks * 32 + lk * 8];
            half8 a1 = *(const half8*)&arow1[kc * 64 + ks * 32 + lk * 8];
            #pragma unroll
            for (int ct = 0; ct < 8; ++ct) {
                half8 b = *(const half8*)&Wsh[cur][wc * 128 + ct * 16 + lrow][ks * 32 + lk * 8];
                acc[0][ct] = __builtin_amdgcn_mfma_f32_16x16x32_f16(a0, b, acc[0][ct], 0, 0, 0);
                acc[1][ct] = __builtin_amdgcn_mfma_f32_16x16x32_f16(a1, b, acc[1][ct], 0, 0, 0);
            }
        }
        if (kc + 1 < 12) {
            #pragma unroll
            for (int j = 0; j < 4; ++j)
                *(half8*)&Wsh[cur ^ 1][pn + j * 64][pc8 * 8] = wreg[j];
        }
    }

    float bo0 = bout[0];
    #pragma unroll
    for (int rt = 0; rt < 2; ++rt) {
        #pragma unroll
        for (int r = 0; r < 4; ++r) {
            float s = 0.f;
            #pragma unroll
            for (int ct = 0; ct < 8; ++ct) {
                int col = wc * 128 + ct * 16 + lrow;
                float v = acc[rt][ct][r] + bi_l[col];
                v = fmaxf(v, 0.f);
                s += v * wo_l[col];
            }
            s += __shfl_xor(s, 1, 64); s += __shfl_xor(s, 2, 64);
            s += __shfl_xor(s, 4, 64); s += __shfl_xor(s, 8, 64);
            if (lrow == 0) part[wr * 32 + rt * 16 + lk * 4 + r][wc] = s;
        }
    }
    ldsbar();
    if (t < 128) out[b0 + t] = part[t][0] + part[t][1] + bo0;
}

// =============== host launcher ===============
extern "C" void kernel_launch(void* const* d_in, const int* in_sizes, int n_in,
                              void* d_out, int out_size, void* d_ws, size_t ws_size,
                              hipStream_t stream)
{
    const float* words = (const float*)d_in[0];
    const float* wq[4] = {(const float*)d_in[1], (const float*)d_in[5], (const float*)d_in[9],  (const float*)d_in[13]};
    const float* bq[4] = {(const float*)d_in[2], (const float*)d_in[6], (const float*)d_in[10], (const float*)d_in[14]};
    const float* wo[4] = {(const float*)d_in[3], (const float*)d_in[7], (const float*)d_in[11], (const float*)d_in[15]};
    const float* bo[4] = {(const float*)d_in[4], (const float*)d_in[8], (const float*)d_in[12], (const float*)d_in[16]};
    const float* wi   = (const float*)d_in[17];
    const float* bi   = (const float*)d_in[18];
    const float* wout = (const float*)d_in[19];
    const float* bout = (const float*)d_in[20];

    char* ws = (char*)d_ws;
    f16*   flat = (f16*)(ws + OFF_FLAT);
    f16*   wiT  = (f16*)(ws + OFF_WIT);
    f16*   wT0  = (f16*)(ws + OFF_WT0);
    f16*   wT1  = (f16*)(ws + OFF_WT1);
    f16*   wT2  = (f16*)(ws + OFF_WT2);
    f16*   wT3  = (f16*)(ws + OFF_WT3);
    float* coA  = (float*)(ws + OFF_CO);
    float* cA   = (float*)(ws + OFF_C);

    pk_fuse<<<dim3(105, 4), 256, 0, stream>>>(
        wq[0], bq[0], wo[0], bo[0], wq[1], bq[1], wo[1], bo[1],
        wq[2], bq[2], wo[2], bo[2], wq[3], bq[3], wo[3], bo[3],
        wT0, wT1, wT2, wT3, coA, cA);
    pk_wit<<<768, 256, 0, stream>>>(wi, wiT);

    // one 16-batch tile per block; dyn LDS = 96*136*2 + 48*72*2 = 33024 B -> 4 blocks/CU
    k1<<<dim3(4096, 4), 256, 33024, stream>>>(words, wT0, wT1, wT2, wT3, coA, cA, flat);

    k2_mlp<<<512, 512, 0, stream>>>(flat, wiT, bi, wout, bout, (float*)d_out);
}